// Round 10
// baseline (177.264 us; speedup 1.0000x reference)
//
#include <hip/hip_runtime.h>

// Chamfer distance — exact, pruned by x-binning (with brute-force fallback
// if the workspace is too small for the sorted copies).
//
// R4-R11 (brute force era): 536.9M pairs, fp32 VALU, 46.3us dispatch floor.
//  - launch_bounds arg2 acts as min BLOCKS/CU ((512,4)->cap 64 VGPR).
//  - pk_fma_f32 = 2x scalar fma cost (packing = zero fp32 throughput).
//  - TLP / reg pipelines / dbuf staging: all null. 3.5 VALU-ops/pair floor.
// R12/R13: x-bin pruning -> container died twice (R13 had ws_size guard).
// Line-audit of the pruned path: no OOB, no divergent barrier, loops
// terminate (<=17 tiles). Infra flakiness is the leading hypothesis (R3:
// 128s pushes). R14: same experiment + hard cap on the outer tile loop
// (34 >= 2x any legitimate count) so ANY unseen hang becomes a finite,
// diagnosable absmax failure instead of a dead container.

#define THREADS 512
#define P 8          // preds per thread (128 per block, 16 lanes x P)
#define G 128        // preds per block
#define NBINS 256
#define XLO -6.0f
#define XHI 6.0f
#define TT 512       // targets per staged tile (pruned path)
#define LSTRIDE17 17 // 16 float4 slice + 1 pad -> disjoint banks per wave
#define MAXTILES 34  // 2*(M/TT)+2 : defensive cap, never binding if correct

// brute-force fallback params (R11)
#define TILE 32
#define LSTRIDE (TILE + 1)
#define TSPLIT 2
#define BUFSZ (32 * LSTRIDE)

typedef float float2_t __attribute__((ext_vector_type(2)));
typedef float float4_t __attribute__((ext_vector_type(4)));

// ---------- pass 1: counting sort by x-bin, emit float4 {x,y,z,|q|^2} ----
__global__ __launch_bounds__(THREADS) void bin_sort_kernel(
    const float* __restrict__ pred, const float* __restrict__ target,
    float4_t* __restrict__ sorted, int* __restrict__ binBase, int M) {
  int bs = blockIdx.x;  // b*2 + side
  int b = bs >> 1, side = bs & 1;
  const float* src = (side ? target : pred) + (size_t)b * M * 3;
  float4_t* out = sorted + (size_t)bs * M;
  int* bases = binBase + bs * (NBINS + 1);

  __shared__ int cnt[NBINS];
  __shared__ int cur[NBINS];
  int t = threadIdx.x;
  for (int i = t; i < NBINS; i += THREADS) cnt[i] = 0;
  __syncthreads();
  const float invW = (float)NBINS / (XHI - XLO);
  for (int i = t; i < M; i += THREADS) {
    float x = src[i * 3];
    int bin = (int)((x - XLO) * invW);
    bin = bin < 0 ? 0 : (bin > NBINS - 1 ? NBINS - 1 : bin);
    atomicAdd(&cnt[bin], 1);
  }
  __syncthreads();
  if (t == 0) {
    int acc = 0;
    for (int i = 0; i < NBINS; ++i) {
      int c = cnt[i];
      cur[i] = acc;
      bases[i] = acc;
      acc += c;
    }
    bases[NBINS] = acc;  // == M
  }
  __syncthreads();
  for (int i = t; i < M; i += THREADS) {
    float x = src[i * 3], y = src[i * 3 + 1], z = src[i * 3 + 2];
    int bin = (int)((x - XLO) * invW);
    bin = bin < 0 ? 0 : (bin > NBINS - 1 ? NBINS - 1 : bin);
    int pos = atomicAdd(&cur[bin], 1);
    out[pos] = (float4_t){x, y, z, x * x + y * y + z * z};
  }
}

// ---------- pass 2: pruned min scan ------------------------------------
__global__ __launch_bounds__(THREADS, 2) void chamfer_min_kernel(
    const float4_t* __restrict__ sorted, const int* __restrict__ binBase,
    float* __restrict__ wsmin, int M) {
  int bid = blockIdx.x;        // pblk + 64*(dir + 2*b)
  int pblk = bid & 63;
  int bd = bid >> 6;
  int dir = bd & 1, b = bd >> 1;
  int srcBS = b * 2 + dir;
  int refBS = b * 2 + (dir ^ 1);
  const float4_t* src = sorted + (size_t)srcBS * M;
  const float4_t* ref = sorted + (size_t)refBS * M;
  const int* rbase = binBase + refBS * (NBINS + 1);

  __shared__ float4_t shbuf[1024];  // 16KB: tile [32][17] (8.7KB) / lmin
  __shared__ float wred[THREADS / 64];
  float4_t* tile = shbuf;

  int t = threadIdx.x;
  int g = t >> 4;   // 0..31: slice group
  int l = t & 15;
  int pbase = pblk * G;

  float ax[P], ay[P], az[P], cm[P], mn[P];
  float pxmn = 1e30f, pxmx = -1e30f;
#pragma unroll
  for (int i = 0; i < P; ++i) {
    float4_t v = src[pbase + l + 16 * i];
    ax[i] = -2.f * v.x;
    ay[i] = -2.f * v.y;
    az[i] = -2.f * v.z;
    cm[i] = v.w;
    mn[i] = 3.0e38f;
    pxmn = fminf(pxmn, v.x);
    pxmx = fmaxf(pxmx, v.x);
  }
  // every wave covers all 128 preds -> wave reduce = block-uniform range
  for (int off = 32; off > 0; off >>= 1) {
    pxmn = fminf(pxmn, __shfl_xor(pxmn, off, 64));
    pxmx = fmaxf(pxmx, __shfl_xor(pxmx, off, 64));
  }

  const float W = (XHI - XLO) / (float)NBINS;
  const float invW = 1.0f / W;
  int cl = (int)((pxmn - XLO) * invW);
  cl = cl < 0 ? 0 : (cl > NBINS - 1 ? NBINS - 1 : cl);
  int cr = cl + 1;
  int offL = 0, offR = 0;

  for (int iter = 0; iter < MAXTILES; ++iter) {  // cap: terminates always
    // ---- stage one tile, pulling bins in outward-gap order (uniform) ----
    int filled = 0;
    while (filled < TT && (cl >= 0 || cr < NBINS)) {
      float gapL = (cl >= 0) ? fmaxf(0.f, pxmn - (XLO + (cl + 1) * W)) : 1e30f;
      float gapR = (cr < NBINS) ? fmaxf(0.f, (XLO + cr * W) - pxmx) : 1e30f;
      bool left = gapL <= gapR;
      int bin = left ? cl : cr;
      int beg = rbase[bin], end = rbase[bin + 1];
      int cnt = end - beg;
      int off = left ? offL : offR;
      int avail = cnt - off;
      int take = avail < (TT - filled) ? avail : (TT - filled);
      for (int i = t; i < take; i += THREADS) {
        int li = filled + i;
        tile[(li >> 4) * LSTRIDE17 + (li & 15)] = ref[beg + off + i];
      }
      filled += take;
      if (left) {
        offL += take;
        if (offL >= cnt) { cl--; offL = 0; }
      } else {
        offR += take;
        if (offR >= cnt) { cr++; offR = 0; }
      }
    }
    for (int i = filled + t; i < TT; i += THREADS) {  // INF pad -> uniform
      tile[(i >> 4) * LSTRIDE17 + (i & 15)] =
          (float4_t){0.f, 0.f, 0.f, 3.0e38f};
    }
    __syncthreads();

    // ---- compute: identical R11 inner loop, 16 targets per group -------
    const float4_t* tp = tile + g * LSTRIDE17;
#pragma unroll 2
    for (int j = 0; j < 16; j += 4) {
      float4_t q0 = tp[j + 0];
      float4_t q1 = tp[j + 1];
      float4_t q2 = tp[j + 2];
      float4_t q3 = tp[j + 3];
#pragma unroll
      for (int i = 0; i < P; ++i) {
        float d0 = fmaf(ax[i], q0.x, fmaf(ay[i], q0.y, fmaf(az[i], q0.z, q0.w)));
        float d1 = fmaf(ax[i], q1.x, fmaf(ay[i], q1.y, fmaf(az[i], q1.z, q1.w)));
        float d2 = fmaf(ax[i], q2.x, fmaf(ay[i], q2.y, fmaf(az[i], q2.z, q2.w)));
        float d3 = fmaf(ax[i], q3.x, fmaf(ay[i], q3.y, fmaf(az[i], q3.z, q3.w)));
        mn[i] = fminf(fminf(mn[i], d0), d1);  // v_min3
        mn[i] = fminf(fminf(mn[i], d2), d3);
      }
    }

    // ---- block-uniform stop test ---------------------------------------
    float tmax = -1e30f;
#pragma unroll
    for (int i = 0; i < P; ++i) tmax = fmaxf(tmax, mn[i] + cm[i]);
    for (int off = 32; off > 0; off >>= 1)
      tmax = fmaxf(tmax, __shfl_xor(tmax, off, 64));
    if ((t & 63) == 0) wred[t >> 6] = tmax;
    __syncthreads();  // also: compute done -> tile safe to overwrite
    float bm = fmaxf(fmaxf(fmaxf(wred[0], wred[1]), fmaxf(wred[2], wred[3])),
                     fmaxf(fmaxf(wred[4], wred[5]), fmaxf(wred[6], wred[7])));
    if (cl < 0 && cr >= NBINS) break;  // scanned everything
    float gapL = (cl >= 0) ? fmaxf(0.f, pxmn - (XLO + (cl + 1) * W)) : 1e30f;
    float gapR = (cr < NBINS) ? fmaxf(0.f, (XLO + cr * W) - pxmx) : 1e30f;
    float gg = fminf(gapL, gapR);
    if (bm <= gg * gg * 0.999f) break;  // excluded d >= gap^2 > bm: exact
  }

  // ---- epilogue: combine 32 slice-mins per pred, add |p|^2 -------------
  float* lmin = (float*)shbuf;  // [32][G]
#pragma unroll
  for (int i = 0; i < P; ++i) lmin[g * G + (l + 16 * i)] = mn[i];
  __syncthreads();
  if (t < G) {
    float m = 3.0e38f;
#pragma unroll
    for (int s = 0; s < 32; ++s) m = fminf(m, lmin[s * G + t]);
    float psq = src[pbase + t].w;  // avoid runtime-indexed cm[] (rule #20)
    wsmin[(size_t)srcBS * M + pbase + t] = psq + m;
  }
}

// ---------- pass 3a: sum wsmin (pruned path) ----------------------------
__global__ __launch_bounds__(256) void chamfer_reduce_kernel(
    const float* __restrict__ wsmin, float* __restrict__ out, int npts,
    float scale) {
  int tid = blockIdx.x * blockDim.x + threadIdx.x;
  int stride = gridDim.x * blockDim.x;
  double acc = 0.0;
  for (int p = tid; p < npts; p += stride) acc += (double)wsmin[p];
  for (int off = 32; off > 0; off >>= 1) acc += __shfl_down(acc, off, 64);
  __shared__ double wsum[256 / 64];
  int t = threadIdx.x;
  if ((t & 63) == 0) wsum[t >> 6] = acc;
  __syncthreads();
  if (t == 0) {
    double s = 0.0;
#pragma unroll
    for (int w = 0; w < 256 / 64; ++w) s += wsum[w];
    atomicAdd(out, (float)(s * (double)scale));
  }
}

// =================== fallback: R11 brute force (512KB ws) ===============
__global__ __launch_bounds__(THREADS, 2) void chamfer_brute_kernel(
    const float* __restrict__ pred, const float* __restrict__ target,
    float* __restrict__ wsmin, int M) {
  const int blocksPerDir = M / G;  // 64
  int bid = blockIdx.x;
  int pblk = bid % blocksPerDir;
  int rest = bid / blocksPerDir;
  int ts = rest % TSPLIT;
  int bd = rest / TSPLIT;
  int dir = bd & 1;
  int b = bd >> 1;
  const float* src = (dir ? target : pred) + (size_t)b * M * 3;
  const float* ref = (dir ? pred : target) + (size_t)b * M * 3;

  __shared__ float4_t lds[2 * BUFSZ];

  int t = threadIdx.x;
  int g = t >> 4;
  int l = t & 15;

  float ax[P], ay[P], az[P];
  int pbase = pblk * G;
#pragma unroll
  for (int i = 0; i < P; ++i) {
    int p = pbase + l + 16 * i;
    float x = src[p * 3 + 0], y = src[p * 3 + 1], z = src[p * 3 + 2];
    ax[i] = -2.f * x;
    ay[i] = -2.f * y;
    az[i] = -2.f * z;
  }
  float mn[P];
#pragma unroll
  for (int i = 0; i < P; ++i) mn[i] = 3.0e38f;

  const int spanLen = M / TSPLIT;
  const int tbase = ts * spanLen;
  const int sliceLen = spanLen / 32;   // 128
  const int ntiles = sliceLen / TILE;  // 4

  const int sidx = 2 * t;
  const int ss = sidx >> 5;
  const int sjj = sidx & (TILE - 1);
  const int nb = tbase + ss * sliceLen + sjj;
  float rx0, ry0, rz0, rx1, ry1, rz1;

  {
    int n = nb;
    rx0 = ref[n * 3 + 0]; ry0 = ref[n * 3 + 1]; rz0 = ref[n * 3 + 2];
    rx1 = ref[n * 3 + 3]; ry1 = ref[n * 3 + 4]; rz1 = ref[n * 3 + 5];
    float4_t* dst = lds + ss * LSTRIDE + sjj;
    dst[0] = (float4_t){rx0, ry0, rz0, rx0 * rx0 + ry0 * ry0 + rz0 * rz0};
    dst[1] = (float4_t){rx1, ry1, rz1, rx1 * rx1 + ry1 * ry1 + rz1 * rz1};
  }
  __syncthreads();

  int cur = 0;
  for (int k = 0; k < ntiles; ++k) {
    if (k + 1 < ntiles) {
      int n = nb + (k + 1) * TILE;
      rx0 = ref[n * 3 + 0]; ry0 = ref[n * 3 + 1]; rz0 = ref[n * 3 + 2];
      rx1 = ref[n * 3 + 3]; ry1 = ref[n * 3 + 4]; rz1 = ref[n * 3 + 5];
    }
    const float4_t* tp = lds + cur * BUFSZ + g * LSTRIDE;
#pragma unroll 2
    for (int j = 0; j < TILE; j += 4) {
      float4_t q0 = tp[j + 0];
      float4_t q1 = tp[j + 1];
      float4_t q2 = tp[j + 2];
      float4_t q3 = tp[j + 3];
#pragma unroll
      for (int i = 0; i < P; ++i) {
        float d0 = fmaf(ax[i], q0.x, fmaf(ay[i], q0.y, fmaf(az[i], q0.z, q0.w)));
        float d1 = fmaf(ax[i], q1.x, fmaf(ay[i], q1.y, fmaf(az[i], q1.z, q1.w)));
        float d2 = fmaf(ax[i], q2.x, fmaf(ay[i], q2.y, fmaf(az[i], q2.z, q2.w)));
        float d3 = fmaf(ax[i], q3.x, fmaf(ay[i], q3.y, fmaf(az[i], q3.z, q3.w)));
        mn[i] = fminf(fminf(mn[i], d0), d1);
        mn[i] = fminf(fminf(mn[i], d2), d3);
      }
    }
    if (k + 1 < ntiles) {
      float4_t* dst = lds + (cur ^ 1) * BUFSZ + ss * LSTRIDE + sjj;
      dst[0] = (float4_t){rx0, ry0, rz0, rx0 * rx0 + ry0 * ry0 + rz0 * rz0};
      dst[1] = (float4_t){rx1, ry1, rz1, rx1 * rx1 + ry1 * ry1 + rz1 * rz1};
    }
    __syncthreads();
    cur ^= 1;
  }

  float* lmin = (float*)lds;
#pragma unroll
  for (int i = 0; i < P; ++i) lmin[g * G + (l + 16 * i)] = mn[i];
  __syncthreads();
  if (t < G) {
    float m = 3.0e38f;
#pragma unroll
    for (int s = 0; s < 32; ++s) m = fminf(m, lmin[s * G + t]);
    int p = pbase + t;
    float x = src[p * 3 + 0], y = src[p * 3 + 1], z = src[p * 3 + 2];
    int pid = (b * 2 + dir) * M + p;
    wsmin[(size_t)pid * TSPLIT + ts] = (x * x + y * y + z * z) + m;
  }
}

// ---------- pass 3b: min over TSPLIT + sum (fallback path) --------------
__global__ __launch_bounds__(256) void chamfer_reduce2_kernel(
    const float* __restrict__ wsmin, float* __restrict__ out, int npts,
    float scale) {
  int tid = blockIdx.x * blockDim.x + threadIdx.x;
  int stride = gridDim.x * blockDim.x;
  double acc = 0.0;
  for (int p = tid; p < npts; p += stride) {
    float2_t v = ((const float2_t*)wsmin)[p];
    acc += (double)fminf(v.x, v.y);
  }
  for (int off = 32; off > 0; off >>= 1) acc += __shfl_down(acc, off, 64);
  __shared__ double wsum[256 / 64];
  int t = threadIdx.x;
  if ((t & 63) == 0) wsum[t >> 6] = acc;
  __syncthreads();
  if (t == 0) {
    double s = 0.0;
#pragma unroll
    for (int w = 0; w < 256 / 64; ++w) s += wsum[w];
    atomicAdd(out, (float)(s * (double)scale));
  }
}

extern "C" void kernel_launch(void* const* d_in, const int* in_sizes, int n_in,
                              void* d_out, int out_size, void* d_ws,
                              size_t ws_size, hipStream_t stream) {
  const float* pred = (const float*)d_in[0];
  const float* target = (const float*)d_in[1];
  float* out = (float*)d_out;
  const int B = 4;
  const int M = in_sizes[0] / (B * 3);  // 8192
  float scale = 1.0f / (float)(B * M);

  hipMemsetAsync(out, 0, sizeof(float), stream);  // d_out is poisoned 0xAA

  // pruned layout: wsmin [B*2*M f32] | sorted [B*2*M float4] | binBase
  size_t needWsmin = (size_t)B * 2 * M * 4;              // 256 KB
  size_t needSorted = (size_t)B * 2 * M * 16;            // 1 MB
  size_t needBins = (size_t)B * 2 * (NBINS + 1) * 4;     // ~8 KB
  size_t need = needWsmin + needSorted + needBins;

  if (ws_size >= need) {
    float* wsmin = (float*)d_ws;
    float4_t* sorted = (float4_t*)((char*)d_ws + needWsmin);
    int* binBase = (int*)((char*)sorted + needSorted);
    bin_sort_kernel<<<B * 2, THREADS, 0, stream>>>(pred, target, sorted,
                                                   binBase, M);
    int blocks = B * 2 * (M / G);  // 512
    chamfer_min_kernel<<<blocks, THREADS, 0, stream>>>(sorted, binBase, wsmin,
                                                       M);
    int npts = B * 2 * M;  // 65536
    chamfer_reduce_kernel<<<64, 256, 0, stream>>>(wsmin, out, npts, scale);
  } else {
    // fallback: R11 brute force, 512 KB ws (known-good at 46.4us dispatch)
    float* wsmin = (float*)d_ws;  // B*2*M*TSPLIT floats = 512 KB
    int blocks = B * 2 * (M / G) * TSPLIT;  // 1024
    chamfer_brute_kernel<<<blocks, THREADS, 0, stream>>>(pred, target, wsmin,
                                                         M);
    int npts = B * 2 * M;
    chamfer_reduce2_kernel<<<64, 256, 0, stream>>>(wsmin, out, npts, scale);
  }
}

// Round 11
// 123.663 us; speedup vs baseline: 1.4334x; 1.4334x over previous
//
#include <hip/hip_runtime.h>

// Chamfer distance — exact, pruned by x-binning (brute-force fallback if
// the workspace can't hold the sorted copies).
//
// R4-R11 (brute force): 46.3us dispatch floor, 3.5 VALU-ops/pair; pk_fma
// is 2x scalar cost (no packed fp32 throughput); TLP/pipelining all null.
// R12/R13: container deaths (infra; kernel audit clean).
// R14: pruned path ran, absmax 0.0, but 115us > brute 46us. VALU work was
// 1.4x brute: the stop test used max over (group,pred) of per-GROUP mins,
// a bound that grows with the scan window itself -> never fires -> full
// scan + serial bin-pull staging tax.
// R15: (a) correct stop: per-tile cross-group reduce through LDS (overlay
// tile buffer) -> bm = max_p of BLOCK-wide best dist^2; per-side gating
// with each side's own gap. bm is fixed once true NNs found (~0.1-0.3)
// while gap grows 0.047/bin -> stops in ~3-6 of 16 tiles. (b) staging =
// two contiguous coalesced copies (frontiers of the bin-sorted array),
// replacing the serial bin-pull. (c) parallel prefix scan in bin_sort.
// Predict: main 115 -> 14-22us, bench ~35-55us, absmax 0.

#define THREADS 512
#define P 8          // preds per thread (128 per block, 16 lanes x P)
#define G 128        // preds per block
#define NBINS 256
#define XLO -6.0f
#define XHI 6.0f
#define TT 512       // targets per staged tile (pruned path)
#define LSTRIDE17 17 // 16 float4 slice + 1 pad -> disjoint banks per wave
#define MAXTILES 34  // 2*(M/TT)+2 : defensive cap, never binding if correct

// brute-force fallback params (R11)
#define TILE 32
#define LSTRIDE (TILE + 1)
#define TSPLIT 2
#define BUFSZ (32 * LSTRIDE)

typedef float float2_t __attribute__((ext_vector_type(2)));
typedef float float4_t __attribute__((ext_vector_type(4)));

// ---------- pass 1: counting sort by x-bin, emit float4 {x,y,z,|q|^2} ----
__global__ __launch_bounds__(THREADS) void bin_sort_kernel(
    const float* __restrict__ pred, const float* __restrict__ target,
    float4_t* __restrict__ sorted, int* __restrict__ binBase, int M) {
  int bs = blockIdx.x;  // b*2 + side
  int b = bs >> 1, side = bs & 1;
  const float* src = (side ? target : pred) + (size_t)b * M * 3;
  float4_t* out = sorted + (size_t)bs * M;
  int* bases = binBase + bs * (NBINS + 1);

  __shared__ int cnt[NBINS];
  __shared__ int scan[NBINS];
  __shared__ int cur[NBINS];
  int t = threadIdx.x;
  for (int i = t; i < NBINS; i += THREADS) cnt[i] = 0;
  __syncthreads();
  const float invW = (float)NBINS / (XHI - XLO);
  for (int i = t; i < M; i += THREADS) {
    float x = src[i * 3];
    int bin = (int)((x - XLO) * invW);
    bin = bin < 0 ? 0 : (bin > NBINS - 1 ? NBINS - 1 : bin);
    atomicAdd(&cnt[bin], 1);
  }
  __syncthreads();
  // parallel inclusive scan (Hillis-Steele) over NBINS=256 counts
  if (t < NBINS) scan[t] = cnt[t];
  __syncthreads();
  for (int off = 1; off < NBINS; off <<= 1) {
    int v = 0;
    if (t < NBINS && t >= off) v = scan[t - off];
    __syncthreads();
    if (t < NBINS) scan[t] += v;
    __syncthreads();
  }
  if (t < NBINS) {
    int excl = scan[t] - cnt[t];
    bases[t] = excl;
    cur[t] = excl;
  }
  if (t == 0) bases[NBINS] = M;
  __syncthreads();
  for (int i = t; i < M; i += THREADS) {
    float x = src[i * 3], y = src[i * 3 + 1], z = src[i * 3 + 2];
    int bin = (int)((x - XLO) * invW);
    bin = bin < 0 ? 0 : (bin > NBINS - 1 ? NBINS - 1 : bin);
    int pos = atomicAdd(&cur[bin], 1);
    out[pos] = (float4_t){x, y, z, x * x + y * y + z * z};
  }
}

// ---------- pass 2: pruned min scan ------------------------------------
__global__ __launch_bounds__(THREADS, 2) void chamfer_min_kernel(
    const float4_t* __restrict__ sorted, const int* __restrict__ binBase,
    float* __restrict__ wsmin, int M) {
  int bid = blockIdx.x;  // pblk + 64*(dir + 2*b)
  int pblk = bid & 63;
  int bd = bid >> 6;
  int dir = bd & 1, b = bd >> 1;
  int srcBS = b * 2 + dir;
  int refBS = b * 2 + (dir ^ 1);
  const float4_t* src = sorted + (size_t)srcBS * M;
  const float4_t* ref = sorted + (size_t)refBS * M;
  const int* rbase = binBase + refBS * (NBINS + 1);

  __shared__ float4_t shbuf[1024];  // 16KB: staged tile / lmin overlay
  __shared__ float wred[THREADS / 64];
  float4_t* tile = shbuf;
  float* lmin = (float*)shbuf;  // [32][G] overlay (tile restaged each iter)

  int t = threadIdx.x;
  int g = t >> 4;  // 0..31: slice group
  int l = t & 15;
  int pbase = pblk * G;

  float ax[P], ay[P], az[P], cm[P], mn[P];
  float pxmn = 1e30f, pxmx = -1e30f;
#pragma unroll
  for (int i = 0; i < P; ++i) {
    float4_t v = src[pbase + l + 16 * i];
    ax[i] = -2.f * v.x;
    ay[i] = -2.f * v.y;
    az[i] = -2.f * v.z;
    cm[i] = v.w;
    mn[i] = 3.0e38f;
    pxmn = fminf(pxmn, v.x);
    pxmx = fmaxf(pxmx, v.x);
  }
  // every wave covers all 128 preds -> wave reduce = block-uniform range
  for (int off = 32; off > 0; off >>= 1) {
    pxmn = fminf(pxmn, __shfl_xor(pxmn, off, 64));
    pxmx = fmaxf(pxmx, __shfl_xor(pxmx, off, 64));
  }

  const float W = (XHI - XLO) / (float)NBINS;
  const float invW = 1.0f / W;
  int cl0 = (int)((pxmn - XLO) * invW);
  cl0 = cl0 < 0 ? 0 : (cl0 > NBINS - 1 ? NBINS - 1 : cl0);
  // left unscanned = [0, Lpos); right unscanned = [Rpos, M)
  int Lpos = rbase[cl0 + 1];
  int Rpos = Lpos;
  int binL = cl0;        // bin containing element Lpos-1 (walked below)
  int binR = cl0 + 1;    // bin containing element Rpos  (walked below)
  float bm = 3.0e38f;    // max over preds of block-wide best dist^2

  for (int iter = 0; iter < MAXTILES; ++iter) {  // cap: always terminates
    // walk bin cursors to current frontier positions (uniform, rbase only)
    while (binL >= 0 && Lpos <= rbase[binL]) --binL;
    while (binR < NBINS && Rpos >= rbase[binR + 1]) ++binR;
    // per-side bounds: left targets have x <= right_edge(binL); right have
    // x >= left_edge(binR)
    float gapL = (Lpos > 0) ? fmaxf(0.f, pxmn - (XLO + (binL + 1) * W))
                            : 3.0e38f;
    float gapR = (Rpos < M) ? fmaxf(0.f, (XLO + binR * W) - pxmx) : 3.0e38f;
    bool leftDone = (Lpos <= 0) || (bm <= 0.999f * gapL * gapL);
    bool rightDone = (Rpos >= M) || (bm <= 0.999f * gapR * gapR);
    if (leftDone && rightDone) break;  // exact: excluded d >= gap^2 > bm

    // ---- stage: two contiguous coalesced copies from the frontiers -----
    int availL = leftDone ? 0 : Lpos;
    int availR = rightDone ? 0 : (M - Rpos);
    int nL = availL < (TT / 2) ? availL : (TT / 2);
    int nR = availR < (TT - nL) ? availR : (TT - nL);
    nL = availL < (TT - nR) ? availL : (TT - nR);  // grant leftover to left
    int lstart = Lpos - nL;
    for (int i = t; i < nL; i += THREADS)
      tile[(i >> 4) * LSTRIDE17 + (i & 15)] = ref[lstart + i];
    for (int i = t; i < nR; i += THREADS) {
      int li = nL + i;
      tile[(li >> 4) * LSTRIDE17 + (li & 15)] = ref[Rpos + i];
    }
    int filled = nL + nR;
    for (int i = filled + t; i < TT; i += THREADS)  // INF pad -> uniform
      tile[(i >> 4) * LSTRIDE17 + (i & 15)] =
          (float4_t){0.f, 0.f, 0.f, 3.0e38f};
    Lpos = lstart;
    Rpos += nR;
    __syncthreads();

    // ---- compute: 16 targets per group, 8 preds per lane ---------------
    const float4_t* tp = tile + g * LSTRIDE17;
#pragma unroll 2
    for (int j = 0; j < 16; j += 4) {
      float4_t q0 = tp[j + 0];
      float4_t q1 = tp[j + 1];
      float4_t q2 = tp[j + 2];
      float4_t q3 = tp[j + 3];
#pragma unroll
      for (int i = 0; i < P; ++i) {
        float d0 = fmaf(ax[i], q0.x, fmaf(ay[i], q0.y, fmaf(az[i], q0.z, q0.w)));
        float d1 = fmaf(ax[i], q1.x, fmaf(ay[i], q1.y, fmaf(az[i], q1.z, q1.w)));
        float d2 = fmaf(ax[i], q2.x, fmaf(ay[i], q2.y, fmaf(az[i], q2.z, q2.w)));
        float d3 = fmaf(ax[i], q3.x, fmaf(ay[i], q3.y, fmaf(az[i], q3.z, q3.w)));
        mn[i] = fminf(fminf(mn[i], d0), d1);  // v_min3
        mn[i] = fminf(fminf(mn[i], d2), d3);
      }
    }

    // ---- cross-group reduce: bm = max_p (block-best dist^2 of p) -------
    __syncthreads();  // compute done before overwriting tile with lmin
#pragma unroll
    for (int i = 0; i < P; ++i) lmin[g * G + (l + 16 * i)] = mn[i];
    __syncthreads();
    float v = -3.0e38f;
    if (t < G) {
      float m2 = 3.0e38f;
#pragma unroll
      for (int s = 0; s < 32; ++s) m2 = fminf(m2, lmin[s * G + t]);
      v = m2 + src[pbase + t].w;  // true dist^2 of pred t's best so far
    }
    for (int off = 32; off > 0; off >>= 1)
      v = fmaxf(v, __shfl_xor(v, off, 64));
    if ((t & 63) == 0) wred[t >> 6] = v;
    __syncthreads();
    bm = fmaxf(fmaxf(fmaxf(wred[0], wred[1]), fmaxf(wred[2], wred[3])),
               fmaxf(fmaxf(wred[4], wred[5]), fmaxf(wred[6], wred[7])));
    // tile contents now garbage (lmin overlay) — restaged next iteration
  }

  // ---- epilogue: combine 32 slice-mins per pred, add |p|^2 -------------
  __syncthreads();
#pragma unroll
  for (int i = 0; i < P; ++i) lmin[g * G + (l + 16 * i)] = mn[i];
  __syncthreads();
  if (t < G) {
    float m = 3.0e38f;
#pragma unroll
    for (int s = 0; s < 32; ++s) m = fminf(m, lmin[s * G + t]);
    float psq = src[pbase + t].w;  // avoid runtime-indexed cm[] (rule #20)
    wsmin[(size_t)srcBS * M + pbase + t] = psq + m;
  }
}

// ---------- pass 3a: sum wsmin (pruned path) ----------------------------
__global__ __launch_bounds__(256) void chamfer_reduce_kernel(
    const float* __restrict__ wsmin, float* __restrict__ out, int npts,
    float scale) {
  int tid = blockIdx.x * blockDim.x + threadIdx.x;
  int stride = gridDim.x * blockDim.x;
  double acc = 0.0;
  for (int p = tid; p < npts; p += stride) acc += (double)wsmin[p];
  for (int off = 32; off > 0; off >>= 1) acc += __shfl_down(acc, off, 64);
  __shared__ double wsum[256 / 64];
  int t = threadIdx.x;
  if ((t & 63) == 0) wsum[t >> 6] = acc;
  __syncthreads();
  if (t == 0) {
    double s = 0.0;
#pragma unroll
    for (int w = 0; w < 256 / 64; ++w) s += wsum[w];
    atomicAdd(out, (float)(s * (double)scale));
  }
}

// =================== fallback: R11 brute force (512KB ws) ===============
__global__ __launch_bounds__(THREADS, 2) void chamfer_brute_kernel(
    const float* __restrict__ pred, const float* __restrict__ target,
    float* __restrict__ wsmin, int M) {
  const int blocksPerDir = M / G;  // 64
  int bid = blockIdx.x;
  int pblk = bid % blocksPerDir;
  int rest = bid / blocksPerDir;
  int ts = rest % TSPLIT;
  int bd = rest / TSPLIT;
  int dir = bd & 1;
  int b = bd >> 1;
  const float* src = (dir ? target : pred) + (size_t)b * M * 3;
  const float* ref = (dir ? pred : target) + (size_t)b * M * 3;

  __shared__ float4_t lds[2 * BUFSZ];

  int t = threadIdx.x;
  int g = t >> 4;
  int l = t & 15;

  float ax[P], ay[P], az[P];
  int pbase = pblk * G;
#pragma unroll
  for (int i = 0; i < P; ++i) {
    int p = pbase + l + 16 * i;
    float x = src[p * 3 + 0], y = src[p * 3 + 1], z = src[p * 3 + 2];
    ax[i] = -2.f * x;
    ay[i] = -2.f * y;
    az[i] = -2.f * z;
  }
  float mn[P];
#pragma unroll
  for (int i = 0; i < P; ++i) mn[i] = 3.0e38f;

  const int spanLen = M / TSPLIT;
  const int tbase = ts * spanLen;
  const int sliceLen = spanLen / 32;   // 128
  const int ntiles = sliceLen / TILE;  // 4

  const int sidx = 2 * t;
  const int ss = sidx >> 5;
  const int sjj = sidx & (TILE - 1);
  const int nb = tbase + ss * sliceLen + sjj;
  float rx0, ry0, rz0, rx1, ry1, rz1;

  {
    int n = nb;
    rx0 = ref[n * 3 + 0]; ry0 = ref[n * 3 + 1]; rz0 = ref[n * 3 + 2];
    rx1 = ref[n * 3 + 3]; ry1 = ref[n * 3 + 4]; rz1 = ref[n * 3 + 5];
    float4_t* dst = lds + ss * LSTRIDE + sjj;
    dst[0] = (float4_t){rx0, ry0, rz0, rx0 * rx0 + ry0 * ry0 + rz0 * rz0};
    dst[1] = (float4_t){rx1, ry1, rz1, rx1 * rx1 + ry1 * ry1 + rz1 * rz1};
  }
  __syncthreads();

  int cur = 0;
  for (int k = 0; k < ntiles; ++k) {
    if (k + 1 < ntiles) {
      int n = nb + (k + 1) * TILE;
      rx0 = ref[n * 3 + 0]; ry0 = ref[n * 3 + 1]; rz0 = ref[n * 3 + 2];
      rx1 = ref[n * 3 + 3]; ry1 = ref[n * 3 + 4]; rz1 = ref[n * 3 + 5];
    }
    const float4_t* tp = lds + cur * BUFSZ + g * LSTRIDE;
#pragma unroll 2
    for (int j = 0; j < TILE; j += 4) {
      float4_t q0 = tp[j + 0];
      float4_t q1 = tp[j + 1];
      float4_t q2 = tp[j + 2];
      float4_t q3 = tp[j + 3];
#pragma unroll
      for (int i = 0; i < P; ++i) {
        float d0 = fmaf(ax[i], q0.x, fmaf(ay[i], q0.y, fmaf(az[i], q0.z, q0.w)));
        float d1 = fmaf(ax[i], q1.x, fmaf(ay[i], q1.y, fmaf(az[i], q1.z, q1.w)));
        float d2 = fmaf(ax[i], q2.x, fmaf(ay[i], q2.y, fmaf(az[i], q2.z, q2.w)));
        float d3 = fmaf(ax[i], q3.x, fmaf(ay[i], q3.y, fmaf(az[i], q3.z, q3.w)));
        mn[i] = fminf(fminf(mn[i], d0), d1);
        mn[i] = fminf(fminf(mn[i], d2), d3);
      }
    }
    if (k + 1 < ntiles) {
      float4_t* dst = lds + (cur ^ 1) * BUFSZ + ss * LSTRIDE + sjj;
      dst[0] = (float4_t){rx0, ry0, rz0, rx0 * rx0 + ry0 * ry0 + rz0 * rz0};
      dst[1] = (float4_t){rx1, ry1, rz1, rx1 * rx1 + ry1 * ry1 + rz1 * rz1};
    }
    __syncthreads();
    cur ^= 1;
  }

  float* lmin = (float*)lds;
#pragma unroll
  for (int i = 0; i < P; ++i) lmin[g * G + (l + 16 * i)] = mn[i];
  __syncthreads();
  if (t < G) {
    float m = 3.0e38f;
#pragma unroll
    for (int s = 0; s < 32; ++s) m = fminf(m, lmin[s * G + t]);
    int p = pbase + t;
    float x = src[p * 3 + 0], y = src[p * 3 + 1], z = src[p * 3 + 2];
    int pid = (b * 2 + dir) * M + p;
    wsmin[(size_t)pid * TSPLIT + ts] = (x * x + y * y + z * z) + m;
  }
}

// ---------- pass 3b: min over TSPLIT + sum (fallback path) --------------
__global__ __launch_bounds__(256) void chamfer_reduce2_kernel(
    const float* __restrict__ wsmin, float* __restrict__ out, int npts,
    float scale) {
  int tid = blockIdx.x * blockDim.x + threadIdx.x;
  int stride = gridDim.x * blockDim.x;
  double acc = 0.0;
  for (int p = tid; p < npts; p += stride) {
    float2_t v = ((const float2_t*)wsmin)[p];
    acc += (double)fminf(v.x, v.y);
  }
  for (int off = 32; off > 0; off >>= 1) acc += __shfl_down(acc, off, 64);
  __shared__ double wsum[256 / 64];
  int t = threadIdx.x;
  if ((t & 63) == 0) wsum[t >> 6] = acc;
  __syncthreads();
  if (t == 0) {
    double s = 0.0;
#pragma unroll
    for (int w = 0; w < 256 / 64; ++w) s += wsum[w];
    atomicAdd(out, (float)(s * (double)scale));
  }
}

extern "C" void kernel_launch(void* const* d_in, const int* in_sizes, int n_in,
                              void* d_out, int out_size, void* d_ws,
                              size_t ws_size, hipStream_t stream) {
  const float* pred = (const float*)d_in[0];
  const float* target = (const float*)d_in[1];
  float* out = (float*)d_out;
  const int B = 4;
  const int M = in_sizes[0] / (B * 3);  // 8192
  float scale = 1.0f / (float)(B * M);

  hipMemsetAsync(out, 0, sizeof(float), stream);  // d_out is poisoned 0xAA

  // pruned layout: wsmin [B*2*M f32] | sorted [B*2*M float4] | binBase
  size_t needWsmin = (size_t)B * 2 * M * 4;           // 256 KB
  size_t needSorted = (size_t)B * 2 * M * 16;         // 1 MB
  size_t needBins = (size_t)B * 2 * (NBINS + 1) * 4;  // ~8 KB
  size_t need = needWsmin + needSorted + needBins;

  if (ws_size >= need) {
    float* wsmin = (float*)d_ws;
    float4_t* sorted = (float4_t*)((char*)d_ws + needWsmin);
    int* binBase = (int*)((char*)sorted + needSorted);
    bin_sort_kernel<<<B * 2, THREADS, 0, stream>>>(pred, target, sorted,
                                                   binBase, M);
    int blocks = B * 2 * (M / G);  // 512
    chamfer_min_kernel<<<blocks, THREADS, 0, stream>>>(sorted, binBase, wsmin,
                                                       M);
    int npts = B * 2 * M;  // 65536
    chamfer_reduce_kernel<<<64, 256, 0, stream>>>(wsmin, out, npts, scale);
  } else {
    // fallback: R11 brute force, 512 KB ws (known-good at 46.4us dispatch)
    float* wsmin = (float*)d_ws;  // B*2*M*TSPLIT floats = 512 KB
    int blocks = B * 2 * (M / G) * TSPLIT;  // 1024
    chamfer_brute_kernel<<<blocks, THREADS, 0, stream>>>(pred, target, wsmin,
                                                         M);
    int npts = B * 2 * M;
    chamfer_reduce2_kernel<<<64, 256, 0, stream>>>(wsmin, out, npts, scale);
  }
}

// Round 12
// 113.378 us; speedup vs baseline: 1.5635x; 1.0907x over previous
//
#include <hip/hip_runtime.h>

// Chamfer distance — exact, pruned by x-binning (brute-force fallback if
// the workspace can't hold the sorted copies).
//
// R4-R11 (brute force): 46.3us dispatch floor; pk_fma = 2x scalar cost;
// TLP/pipelining all null. launch_bounds arg2 = min BLOCKS/CU; empirical
// VGPR cap = 2048 / (arg2 x waves_per_block).
// R14: stop test too weak (per-group mins) -> full scan, 115us.
// R15: block-wide stop: 58us, absmax 0. Counters: true VALU 11us (46%
// scan — y/z-outlier preds force wide x-windows) + 47us OVERHEAD:
// LDS reduce (8 wr + 32 serial rd + 4 barriers/tile), serial dependent-L2
// bin-cursor walk, 512-block one-round packing (occupancy 18%).
// R16 (this): overhead attack. 256 thr / 64 preds / 1024 blocks (6/CU);
// thread = 2 preds x 64 targets; 8-thread clusters are consecutive lanes
// -> per-pred min + stop bound via 6 shfl_xor + wred[4]; 2 barriers/tile.
// Tile [8][65] float4 -> 8 rows hit banks {0,4..28}: conflict-free.
// Frontier-x gaps (one load/side, no bin walk): gapL = pxmn-(x[Lpos-1]+W)
// is exact since bin-sorted. Predict: main 58 -> 20-32us, bench ~60-78.

#define NBINS 256
#define XLO -6.0f
#define XHI 6.0f
#define TT 512        // targets per staged tile (pruned path)
#define GP 64         // preds per block (pruned path)
#define TP 256        // threads (pruned path)
#define MAXTILES 34   // defensive cap, never binding if correct

// brute-force fallback params (R11, unchanged)
#define THREADS 512
#define P 8
#define G 128
#define TILE 32
#define LSTRIDE (TILE + 1)
#define TSPLIT 2
#define BUFSZ (32 * LSTRIDE)

typedef float float2_t __attribute__((ext_vector_type(2)));
typedef float float4_t __attribute__((ext_vector_type(4)));

// ---------- pass 1: counting sort by x-bin, emit float4 {x,y,z,|q|^2} ----
__global__ __launch_bounds__(THREADS) void bin_sort_kernel(
    const float* __restrict__ pred, const float* __restrict__ target,
    float4_t* __restrict__ sorted, int* __restrict__ binBase, int M) {
  int bs = blockIdx.x;  // b*2 + side
  int b = bs >> 1, side = bs & 1;
  const float* src = (side ? target : pred) + (size_t)b * M * 3;
  float4_t* out = sorted + (size_t)bs * M;
  int* bases = binBase + bs * (NBINS + 1);

  __shared__ int cnt[NBINS];
  __shared__ int scan[NBINS];
  __shared__ int cur[NBINS];
  int t = threadIdx.x;
  for (int i = t; i < NBINS; i += THREADS) cnt[i] = 0;
  __syncthreads();
  const float invW = (float)NBINS / (XHI - XLO);
  for (int i = t; i < M; i += THREADS) {
    float x = src[i * 3];
    int bin = (int)((x - XLO) * invW);
    bin = bin < 0 ? 0 : (bin > NBINS - 1 ? NBINS - 1 : bin);
    atomicAdd(&cnt[bin], 1);
  }
  __syncthreads();
  // parallel inclusive scan (Hillis-Steele) over NBINS=256 counts
  if (t < NBINS) scan[t] = cnt[t];
  __syncthreads();
  for (int off = 1; off < NBINS; off <<= 1) {
    int v = 0;
    if (t < NBINS && t >= off) v = scan[t - off];
    __syncthreads();
    if (t < NBINS) scan[t] += v;
    __syncthreads();
  }
  if (t < NBINS) {
    int excl = scan[t] - cnt[t];
    bases[t] = excl;
    cur[t] = excl;
  }
  if (t == 0) bases[NBINS] = M;
  __syncthreads();
  for (int i = t; i < M; i += THREADS) {
    float x = src[i * 3], y = src[i * 3 + 1], z = src[i * 3 + 2];
    int bin = (int)((x - XLO) * invW);
    bin = bin < 0 ? 0 : (bin > NBINS - 1 ? NBINS - 1 : bin);
    int pos = atomicAdd(&cur[bin], 1);
    out[pos] = (float4_t){x, y, z, x * x + y * y + z * z};
  }
}

// ---------- pass 2: pruned min scan (cluster-shuffle version) -----------
__global__ __launch_bounds__(TP, 6) void chamfer_min_kernel(
    const float4_t* __restrict__ sorted, const int* __restrict__ binBase,
    float* __restrict__ wsmin, int M) {
  int bid = blockIdx.x;  // pblk + 128*(dir + 2*b)
  int pblk = bid & 127;
  int bd = bid >> 7;
  int dir = bd & 1, b = bd >> 1;
  int srcBS = b * 2 + dir;
  int refBS = b * 2 + (dir ^ 1);
  const float4_t* src = sorted + (size_t)srcBS * M;
  const float4_t* ref = sorted + (size_t)refBS * M;
  const int* rbase = binBase + refBS * (NBINS + 1);

  __shared__ float4_t tile[8 * 65];  // 8320 B; rows at banks {0,4,..,28}
  __shared__ float wred[TP / 64];

  int t = threadIdx.x;
  int c = t >> 3;  // cluster 0..31 (8 consecutive lanes — same wave)
  int r = t & 7;   // target-row 0..7
  int pbase = pblk * GP;

  // two preds per thread: c and c+32
  float4_t v0 = src[pbase + c];
  float4_t v1 = src[pbase + c + 32];
  float ax0 = -2.f * v0.x, ay0 = -2.f * v0.y, az0 = -2.f * v0.z, cm0 = v0.w;
  float ax1 = -2.f * v1.x, ay1 = -2.f * v1.y, az1 = -2.f * v1.z, cm1 = v1.w;
  float mn0 = 3.0e38f, mn1 = 3.0e38f;

  const float W = (XHI - XLO) / (float)NBINS;
  // conservative slab bounds from bin-sortedness (no reduce needed)
  float pxmn = src[pbase].x - W;
  float pxmx = src[pbase + GP - 1].x + W;

  int cl0 = (int)((pxmn - XLO) * (1.0f / W));
  cl0 = cl0 < 0 ? 0 : (cl0 > NBINS - 1 ? NBINS - 1 : cl0);
  int Lpos = rbase[cl0 + 1];  // left unscanned = [0,Lpos)
  int Rpos = Lpos;            // right unscanned = [Rpos,M)
  float bm = 3.0e38f;         // max over preds of block-best dist^2

  for (int iter = 0; iter < MAXTILES; ++iter) {  // cap: always terminates
    // frontier-x gap bounds: unscanned-left x <= ref[Lpos-1].x + W (bin-
    // sorted); unscanned-right x >= ref[Rpos].x - W. One load per side.
    float gapL = 3.0e38f, gapR = 3.0e38f;
    if (Lpos > 0) gapL = fmaxf(0.f, pxmn - (ref[Lpos - 1].x + W));
    if (Rpos < M) gapR = fmaxf(0.f, (ref[Rpos].x - W) - pxmx);
    bool leftDone = (Lpos <= 0) || (bm <= 0.999f * gapL * gapL);
    bool rightDone = (Rpos >= M) || (bm <= 0.999f * gapR * gapR);
    if (leftDone && rightDone) break;  // exact: excluded d^2 >= gap^2 > bm

    int availL = leftDone ? 0 : Lpos;
    int availR = rightDone ? 0 : (M - Rpos);
    int nL = availL < (TT / 2) ? availL : (TT / 2);
    int nR = availR < (TT - nL) ? availR : (TT - nL);
    nL = availL < (TT - nR) ? availL : (TT - nR);
    int lstart = Lpos - nL;
    int filled = nL + nR;
#pragma unroll
    for (int k = 0; k < TT / TP; ++k) {  // 2 entries per thread
      int i = t + TP * k;
      float4_t q = (float4_t){0.f, 0.f, 0.f, 3.0e38f};
      if (i < filled) {
        int idx = (i < nL) ? (lstart + i) : (Rpos + (i - nL));
        q = ref[idx];
      }
      tile[(i >> 6) * 65 + (i & 63)] = q;
    }
    Lpos = lstart;
    Rpos += nR;
    __syncthreads();

    // compute: row r scans targets [r*64, r*64+64) for preds c, c+32
    const float4_t* tp = tile + r * 65;
#pragma unroll 2
    for (int j = 0; j < 64; j += 4) {
      float4_t q0 = tp[j + 0];
      float4_t q1 = tp[j + 1];
      float4_t q2 = tp[j + 2];
      float4_t q3 = tp[j + 3];
      float d00 = fmaf(ax0, q0.x, fmaf(ay0, q0.y, fmaf(az0, q0.z, q0.w)));
      float d01 = fmaf(ax0, q1.x, fmaf(ay0, q1.y, fmaf(az0, q1.z, q1.w)));
      float d02 = fmaf(ax0, q2.x, fmaf(ay0, q2.y, fmaf(az0, q2.z, q2.w)));
      float d03 = fmaf(ax0, q3.x, fmaf(ay0, q3.y, fmaf(az0, q3.z, q3.w)));
      mn0 = fminf(fminf(mn0, d00), d01);  // v_min3
      mn0 = fminf(fminf(mn0, d02), d03);
      float d10 = fmaf(ax1, q0.x, fmaf(ay1, q0.y, fmaf(az1, q0.z, q0.w)));
      float d11 = fmaf(ax1, q1.x, fmaf(ay1, q1.y, fmaf(az1, q1.z, q1.w)));
      float d12 = fmaf(ax1, q2.x, fmaf(ay1, q2.y, fmaf(az1, q2.z, q2.w)));
      float d13 = fmaf(ax1, q3.x, fmaf(ay1, q3.y, fmaf(az1, q3.z, q3.w)));
      mn1 = fminf(fminf(mn1, d10), d11);
      mn1 = fminf(fminf(mn1, d12), d13);
    }

    // stop bound: cluster-min (xor 1,2,4) then wave-max (xor 8,16,32)
    float f0 = mn0, f1 = mn1;
    f0 = fminf(f0, __shfl_xor(f0, 1, 64));
    f0 = fminf(f0, __shfl_xor(f0, 2, 64));
    f0 = fminf(f0, __shfl_xor(f0, 4, 64));
    f1 = fminf(f1, __shfl_xor(f1, 1, 64));
    f1 = fminf(f1, __shfl_xor(f1, 2, 64));
    f1 = fminf(f1, __shfl_xor(f1, 4, 64));
    float vv = fmaxf(f0 + cm0, f1 + cm1);
    vv = fmaxf(vv, __shfl_xor(vv, 8, 64));
    vv = fmaxf(vv, __shfl_xor(vv, 16, 64));
    vv = fmaxf(vv, __shfl_xor(vv, 32, 64));
    if ((t & 63) == 0) wred[t >> 6] = vv;
    __syncthreads();  // compute done (tile safe to overwrite) + wred ready
    bm = fmaxf(fmaxf(wred[0], wred[1]), fmaxf(wred[2], wred[3]));
  }

  // epilogue: cluster-combine and write 2 preds per r==0 thread
  float f0 = mn0, f1 = mn1;
  f0 = fminf(f0, __shfl_xor(f0, 1, 64));
  f0 = fminf(f0, __shfl_xor(f0, 2, 64));
  f0 = fminf(f0, __shfl_xor(f0, 4, 64));
  f1 = fminf(f1, __shfl_xor(f1, 1, 64));
  f1 = fminf(f1, __shfl_xor(f1, 2, 64));
  f1 = fminf(f1, __shfl_xor(f1, 4, 64));
  if (r == 0) {
    wsmin[(size_t)srcBS * M + pbase + c] = f0 + cm0;
    wsmin[(size_t)srcBS * M + pbase + c + 32] = f1 + cm1;
  }
}

// ---------- pass 3a: sum wsmin (pruned path) ----------------------------
__global__ __launch_bounds__(256) void chamfer_reduce_kernel(
    const float* __restrict__ wsmin, float* __restrict__ out, int npts,
    float scale) {
  int tid = blockIdx.x * blockDim.x + threadIdx.x;
  int stride = gridDim.x * blockDim.x;
  double acc = 0.0;
  for (int p = tid; p < npts; p += stride) acc += (double)wsmin[p];
  for (int off = 32; off > 0; off >>= 1) acc += __shfl_down(acc, off, 64);
  __shared__ double wsum[256 / 64];
  int t = threadIdx.x;
  if ((t & 63) == 0) wsum[t >> 6] = acc;
  __syncthreads();
  if (t == 0) {
    double s = 0.0;
#pragma unroll
    for (int w = 0; w < 256 / 64; ++w) s += wsum[w];
    atomicAdd(out, (float)(s * (double)scale));
  }
}

// =================== fallback: R11 brute force (512KB ws) ===============
__global__ __launch_bounds__(THREADS, 2) void chamfer_brute_kernel(
    const float* __restrict__ pred, const float* __restrict__ target,
    float* __restrict__ wsmin, int M) {
  const int blocksPerDir = M / G;  // 64
  int bid = blockIdx.x;
  int pblk = bid % blocksPerDir;
  int rest = bid / blocksPerDir;
  int ts = rest % TSPLIT;
  int bd = rest / TSPLIT;
  int dir = bd & 1;
  int b = bd >> 1;
  const float* src = (dir ? target : pred) + (size_t)b * M * 3;
  const float* ref = (dir ? pred : target) + (size_t)b * M * 3;

  __shared__ float4_t lds[2 * BUFSZ];

  int t = threadIdx.x;
  int g = t >> 4;
  int l = t & 15;

  float ax[P], ay[P], az[P];
  int pbase = pblk * G;
#pragma unroll
  for (int i = 0; i < P; ++i) {
    int p = pbase + l + 16 * i;
    float x = src[p * 3 + 0], y = src[p * 3 + 1], z = src[p * 3 + 2];
    ax[i] = -2.f * x;
    ay[i] = -2.f * y;
    az[i] = -2.f * z;
  }
  float mn[P];
#pragma unroll
  for (int i = 0; i < P; ++i) mn[i] = 3.0e38f;

  const int spanLen = M / TSPLIT;
  const int tbase = ts * spanLen;
  const int sliceLen = spanLen / 32;   // 128
  const int ntiles = sliceLen / TILE;  // 4

  const int sidx = 2 * t;
  const int ss = sidx >> 5;
  const int sjj = sidx & (TILE - 1);
  const int nb = tbase + ss * sliceLen + sjj;
  float rx0, ry0, rz0, rx1, ry1, rz1;

  {
    int n = nb;
    rx0 = ref[n * 3 + 0]; ry0 = ref[n * 3 + 1]; rz0 = ref[n * 3 + 2];
    rx1 = ref[n * 3 + 3]; ry1 = ref[n * 3 + 4]; rz1 = ref[n * 3 + 5];
    float4_t* dst = lds + ss * LSTRIDE + sjj;
    dst[0] = (float4_t){rx0, ry0, rz0, rx0 * rx0 + ry0 * ry0 + rz0 * rz0};
    dst[1] = (float4_t){rx1, ry1, rz1, rx1 * rx1 + ry1 * ry1 + rz1 * rz1};
  }
  __syncthreads();

  int cur = 0;
  for (int k = 0; k < ntiles; ++k) {
    if (k + 1 < ntiles) {
      int n = nb + (k + 1) * TILE;
      rx0 = ref[n * 3 + 0]; ry0 = ref[n * 3 + 1]; rz0 = ref[n * 3 + 2];
      rx1 = ref[n * 3 + 3]; ry1 = ref[n * 3 + 4]; rz1 = ref[n * 3 + 5];
    }
    const float4_t* tp = lds + cur * BUFSZ + g * LSTRIDE;
#pragma unroll 2
    for (int j = 0; j < TILE; j += 4) {
      float4_t q0 = tp[j + 0];
      float4_t q1 = tp[j + 1];
      float4_t q2 = tp[j + 2];
      float4_t q3 = tp[j + 3];
#pragma unroll
      for (int i = 0; i < P; ++i) {
        float d0 = fmaf(ax[i], q0.x, fmaf(ay[i], q0.y, fmaf(az[i], q0.z, q0.w)));
        float d1 = fmaf(ax[i], q1.x, fmaf(ay[i], q1.y, fmaf(az[i], q1.z, q1.w)));
        float d2 = fmaf(ax[i], q2.x, fmaf(ay[i], q2.y, fmaf(az[i], q2.z, q2.w)));
        float d3 = fmaf(ax[i], q3.x, fmaf(ay[i], q3.y, fmaf(az[i], q3.z, q3.w)));
        mn[i] = fminf(fminf(mn[i], d0), d1);
        mn[i] = fminf(fminf(mn[i], d2), d3);
      }
    }
    if (k + 1 < ntiles) {
      float4_t* dst = lds + (cur ^ 1) * BUFSZ + ss * LSTRIDE + sjj;
      dst[0] = (float4_t){rx0, ry0, rz0, rx0 * rx0 + ry0 * ry0 + rz0 * rz0};
      dst[1] = (float4_t){rx1, ry1, rz1, rx1 * rx1 + ry1 * ry1 + rz1 * rz1};
    }
    __syncthreads();
    cur ^= 1;
  }

  float* lmin = (float*)lds;
#pragma unroll
  for (int i = 0; i < P; ++i) lmin[g * G + (l + 16 * i)] = mn[i];
  __syncthreads();
  if (t < G) {
    float m = 3.0e38f;
#pragma unroll
    for (int s = 0; s < 32; ++s) m = fminf(m, lmin[s * G + t]);
    int p = pbase + t;
    float x = src[p * 3 + 0], y = src[p * 3 + 1], z = src[p * 3 + 2];
    int pid = (b * 2 + dir) * M + p;
    wsmin[(size_t)pid * TSPLIT + ts] = (x * x + y * y + z * z) + m;
  }
}

// ---------- pass 3b: min over TSPLIT + sum (fallback path) --------------
__global__ __launch_bounds__(256) void chamfer_reduce2_kernel(
    const float* __restrict__ wsmin, float* __restrict__ out, int npts,
    float scale) {
  int tid = blockIdx.x * blockDim.x + threadIdx.x;
  int stride = gridDim.x * blockDim.x;
  double acc = 0.0;
  for (int p = tid; p < npts; p += stride) {
    float2_t v = ((const float2_t*)wsmin)[p];
    acc += (double)fminf(v.x, v.y);
  }
  for (int off = 32; off > 0; off >>= 1) acc += __shfl_down(acc, off, 64);
  __shared__ double wsum[256 / 64];
  int t = threadIdx.x;
  if ((t & 63) == 0) wsum[t >> 6] = acc;
  __syncthreads();
  if (t == 0) {
    double s = 0.0;
#pragma unroll
    for (int w = 0; w < 256 / 64; ++w) s += wsum[w];
    atomicAdd(out, (float)(s * (double)scale));
  }
}

extern "C" void kernel_launch(void* const* d_in, const int* in_sizes, int n_in,
                              void* d_out, int out_size, void* d_ws,
                              size_t ws_size, hipStream_t stream) {
  const float* pred = (const float*)d_in[0];
  const float* target = (const float*)d_in[1];
  float* out = (float*)d_out;
  const int B = 4;
  const int M = in_sizes[0] / (B * 3);  // 8192
  float scale = 1.0f / (float)(B * M);

  hipMemsetAsync(out, 0, sizeof(float), stream);  // d_out is poisoned 0xAA

  // pruned layout: wsmin [B*2*M f32] | sorted [B*2*M float4] | binBase
  size_t needWsmin = (size_t)B * 2 * M * 4;           // 256 KB
  size_t needSorted = (size_t)B * 2 * M * 16;         // 1 MB
  size_t needBins = (size_t)B * 2 * (NBINS + 1) * 4;  // ~8 KB
  size_t need = needWsmin + needSorted + needBins;

  if (ws_size >= need) {
    float* wsmin = (float*)d_ws;
    float4_t* sorted = (float4_t*)((char*)d_ws + needWsmin);
    int* binBase = (int*)((char*)sorted + needSorted);
    bin_sort_kernel<<<B * 2, THREADS, 0, stream>>>(pred, target, sorted,
                                                   binBase, M);
    int blocks = B * 2 * (M / GP);  // 1024
    chamfer_min_kernel<<<blocks, TP, 0, stream>>>(sorted, binBase, wsmin, M);
    int npts = B * 2 * M;  // 65536
    chamfer_reduce_kernel<<<64, 256, 0, stream>>>(wsmin, out, npts, scale);
  } else {
    // fallback: R11 brute force, 512 KB ws (known-good at 46.4us dispatch)
    float* wsmin = (float*)d_ws;  // B*2*M*TSPLIT floats = 512 KB
    int blocks = B * 2 * (M / G) * TSPLIT;  // 1024
    chamfer_brute_kernel<<<blocks, THREADS, 0, stream>>>(pred, target, wsmin,
                                                         M);
    int npts = B * 2 * M;
    chamfer_reduce2_kernel<<<64, 256, 0, stream>>>(wsmin, out, npts, scale);
  }
}